// Round 6
// baseline (800.481 us; speedup 1.0000x reference)
//
#include <hip/hip_runtime.h>
#include <stdint.h>

#define DEVI static __device__ __forceinline__

typedef __attribute__((ext_vector_type(8))) short short8;
typedef __attribute__((ext_vector_type(4))) float floatx4;
typedef __attribute__((ext_vector_type(4))) unsigned short ushortx4;

// ---------- bf16 helpers ----------
DEVI unsigned short f2bf(float f) {
  union { float f; uint32_t u; } v; v.f = f;
  uint32_t r = v.u + 0x7FFFu + ((v.u >> 16) & 1u);
  return (unsigned short)(r >> 16);
}
DEVI float bf2f(unsigned short s) {
  union { uint32_t u; float f; } v; v.u = ((uint32_t)s) << 16;
  return v.f;
}

// =====================================================================
// f32 -> bf16 for Q (first 8192 blocks) and K (next 16384 blocks)
// =====================================================================
__global__ __launch_bounds__(256) void cvt_qk(const float* __restrict__ Q,
                                              const float* __restrict__ K,
                                              unsigned short* __restrict__ Qb,
                                              unsigned short* __restrict__ Kb) {
  const int bid = blockIdx.x;
  const float* src;
  unsigned short* dst;
  size_t i;
  if (bid < 8192) { src = Q; dst = Qb; i = (size_t)bid * 256 + threadIdx.x; }
  else            { src = K; dst = Kb; i = (size_t)(bid - 8192) * 256 + threadIdx.x; }
  const floatx4 v = ((const floatx4*)src)[i];
  ushortx4 o;
  o.x = f2bf(v.x); o.y = f2bf(v.y); o.z = f2bf(v.z); o.w = f2bf(v.w);
  ((ushortx4*)dst)[i] = o;
}

// =====================================================================
// All 4 weight transposes in one launch. z: 0=Wq,1=Wk,2=Wv,3=Wo.
// =====================================================================
__global__ __launch_bounds__(256) void wtrans4(const float* __restrict__ Wq,
                                               const float* __restrict__ Wk,
                                               const float* __restrict__ Wv,
                                               const float* __restrict__ Wo,
                                               unsigned short* __restrict__ Wt) {
  __shared__ float t[32][33];
  const int tx = threadIdx.x, ty = threadIdx.y;
  const int z = blockIdx.z;
  const float* W = (z == 0) ? Wq : (z == 1) ? Wk : (z == 2) ? Wv : Wo;
  unsigned short* D = Wt + (size_t)z * 1024 * 1024;
  const int c0 = blockIdx.x * 32, r0 = blockIdx.y * 32;
#pragma unroll
  for (int i = 0; i < 4; i++)
    t[ty + i * 8][tx] = W[(size_t)(r0 + ty + i * 8) * 1024 + c0 + tx];
  __syncthreads();
#pragma unroll
  for (int i = 0; i < 4; i++)
    D[(size_t)(c0 + ty + i * 8) * 1024 + r0 + tx] = f2bf(t[tx][ty + i * 8]);
}

// ---------- register-direct GEMM core macros ----------
// A-frag rows stride 16*1024 elems; 16B per lane at (row)*1024 + qd*8.
#define LD_AB(av, bv, K0)                                                      \
  {                                                                            \
    _Pragma("unroll") for (int i = 0; i < 4; i++) {                            \
      av[i] = *(const short8*)(ap + (size_t)i * 16384 + (K0));                 \
      bv[i] = *(const short8*)(bp + (size_t)i * 16384 + (K0));                 \
    }                                                                          \
  }
#define MFMA16(av, bv)                                                         \
  {                                                                            \
    _Pragma("unroll") for (int mi = 0; mi < 4; mi++)                           \
        _Pragma("unroll") for (int ni = 0; ni < 4; ni++) acc[mi][ni] =         \
        __builtin_amdgcn_mfma_f32_16x16x32_bf16(av[mi], bv[ni], acc[mi][ni],   \
                                                0, 0, 0);                      \
  }

// =====================================================================
// Register-direct GEMM, 128x128 block tile, 4 waves of 64x64, NO LDS,
// NO barriers: each wave loads its own A/B fragments global->VGPR and
// the compiler pipelines with vmcnt(N). XCD m-banded swizzle (BSH:
// band = 1<<BSH m-tiles per XCD).
// EPI: 0 = bf16 rowmajor out; 2 = f32 out, fused O2 = X1 + relu(acc+bias)
// =====================================================================
template <int EPI, int BSH>
__global__ __launch_bounds__(256, 2) void gemm_rd(
    const unsigned short* __restrict__ A, const unsigned short* __restrict__ Bt,
    const float* __restrict__ bias, const unsigned short* __restrict__ X1,
    void* __restrict__ Cout) {
  const int tid = threadIdx.x;
  const int lane = tid & 63, w = tid >> 6;
  const int wr = w >> 1, wc = w & 1;
  const int qd = lane >> 4, l16 = lane & 15;
  const int bid = blockIdx.x;
  const int xcd = bid & 7, loc = bid >> 3;
  const int mt = xcd * (1 << BSH) + (loc & ((1 << BSH) - 1));
  const int nt = loc >> BSH;
  const int m0 = mt * 128, n0 = nt * 128;

  const unsigned short* ap = A + (size_t)(m0 + wr * 64 + l16) * 1024 + qd * 8;
  const unsigned short* bp = Bt + (size_t)(n0 + wc * 64 + l16) * 1024 + qd * 8;

  floatx4 acc[4][4];
#pragma unroll
  for (int i = 0; i < 4; i++)
#pragma unroll
    for (int j = 0; j < 4; j++) { floatx4 z = {0.f, 0.f, 0.f, 0.f}; acc[i][j] = z; }

  short8 a0[4], b0[4], a1[4], b1[4];
  LD_AB(a0, b0, 0)
  for (int it = 0; it < 32; it += 2) {
    LD_AB(a1, b1, (it + 1) * 32)
    MFMA16(a0, b0)
    if (it + 2 < 32) LD_AB(a0, b0, (it + 2) * 32)
    MFMA16(a1, b1)
  }

#pragma unroll
  for (int mi = 0; mi < 4; mi++) {
#pragma unroll
    for (int ni = 0; ni < 4; ni++) {
      const int row = m0 + wr * 64 + mi * 16 + qd * 4;
      const int col = n0 + wc * 64 + ni * 16 + l16;
      const float bv = bias[col];
      if constexpr (EPI == 0) {
        unsigned short* C = (unsigned short*)Cout;
#pragma unroll
        for (int r = 0; r < 4; r++)
          C[(size_t)(row + r) * 1024 + col] = f2bf(acc[mi][ni][r] + bv);
      } else {
        float* C = (float*)Cout;
#pragma unroll
        for (int r = 0; r < 4; r++) {
          const float x1 = bf2f(X1[(size_t)(row + r) * 1024 + col]);
          C[(size_t)(row + r) * 1024 + col] = x1 + fmaxf(acc[mi][ni][r] + bv, 0.f);
        }
      }
    }
  }
}

// =====================================================================
// Register-direct KV GEMM (M=16384, N=2048): same core, BSH=4 banding.
// cols <1024 -> kbp bf16 rowmajor (+bk); cols >=1024 -> vt[b][h][dh][nk] (+bv)
// =====================================================================
__global__ __launch_bounds__(256, 2) void gemm_kv_rd(
    const unsigned short* __restrict__ A, const unsigned short* __restrict__ Bt,
    const float* __restrict__ biasK, const float* __restrict__ biasV,
    unsigned short* __restrict__ CK, unsigned short* __restrict__ CV) {
  const int tid = threadIdx.x;
  const int lane = tid & 63, w = tid >> 6;
  const int wr = w >> 1, wc = w & 1;
  const int qd = lane >> 4, l16 = lane & 15;
  const int bid = blockIdx.x;
  const int xcd = bid & 7, loc = bid >> 3;
  const int mt = xcd * 16 + (loc & 15);
  const int nt = loc >> 4;
  const int m0 = mt * 128, n0 = nt * 128;

  const unsigned short* ap = A + (size_t)(m0 + wr * 64 + l16) * 1024 + qd * 8;
  const unsigned short* bp = Bt + (size_t)(n0 + wc * 64 + l16) * 1024 + qd * 8;

  floatx4 acc[4][4];
#pragma unroll
  for (int i = 0; i < 4; i++)
#pragma unroll
    for (int j = 0; j < 4; j++) { floatx4 z = {0.f, 0.f, 0.f, 0.f}; acc[i][j] = z; }

  short8 a0[4], b0[4], a1[4], b1[4];
  LD_AB(a0, b0, 0)
  for (int it = 0; it < 32; it += 2) {
    LD_AB(a1, b1, (it + 1) * 32)
    MFMA16(a0, b0)
    if (it + 2 < 32) LD_AB(a0, b0, (it + 2) * 32)
    MFMA16(a1, b1)
  }

#pragma unroll
  for (int mi = 0; mi < 4; mi++) {
#pragma unroll
    for (int ni = 0; ni < 4; ni++) {
      const int row = m0 + wr * 64 + mi * 16 + qd * 4;
      const int col = n0 + wc * 64 + ni * 16 + l16;
      if (col < 1024) {  // K half (wave-uniform: col block is 16-aligned within nt)
        const float bv = biasK[col];
#pragma unroll
        for (int r = 0; r < 4; r++)
          CK[(size_t)(row + r) * 1024 + col] = f2bf(acc[mi][ni][r] + bv);
      } else {  // V half -> vt[b][h][dh][nk]
        const int vc = col - 1024;
        const float bv = biasV[vc];
        const int bb = row >> 11, nk = row & 2047;
        const int hh = vc >> 7, dh = vc & 127;
        ushortx4 pk;
        pk.x = f2bf(acc[mi][ni][0] + bv);
        pk.y = f2bf(acc[mi][ni][1] + bv);
        pk.z = f2bf(acc[mi][ni][2] + bv);
        pk.w = f2bf(acc[mi][ni][3] + bv);
        *(ushortx4*)&CV[(size_t)((bb * 8 + hh) * 128 + dh) * 2048 + nk] = pk;
      }
    }
  }
}

// =====================================================================
// Flash attention, register-direct & BARRIER-FREE: Q/K/V fragments loaded
// global->VGPR per wave; P round-trips through wave-private LDS (lgkmcnt
// ordering only, no __syncthreads anywhere). 128 q-rows/block (4 waves x
// 32 rows), BN=32 KV steps. XCD-swizzled grid (bid%8 = b).
// =====================================================================
__global__ __launch_bounds__(256, 2) void attn(
    const unsigned short* __restrict__ qb, const unsigned short* __restrict__ kb,
    const unsigned short* __restrict__ vt, unsigned short* __restrict__ Ob) {
  __shared__ unsigned short Ps[4096];  // [chunk 0..3][q-row 0..127][8] — wave-private rows

  const int tid = threadIdx.x;
  const int lane = tid & 63, w = tid >> 6;
  const int qd = lane >> 4, l16 = lane & 15;
  const int bid = blockIdx.x;
  const int qt = bid >> 6, bh = bid & 63;
  const int h = bh >> 3, b = bh & 7;
  const int m0 = qt * 128;

  const size_t qbase = ((size_t)(b * 1024 + m0)) * 1024 + h * 128;
  const size_t kbase = ((size_t)(b * 2048)) * 1024 + h * 128;
  const size_t vbase = ((size_t)((b * 8 + h) * 128)) * 2048;

  // Q fragments direct from global (wave-local rows w*32 + mi*16 + l16)
  const unsigned short* qp = qb + qbase + (size_t)(w * 32 + l16) * 1024 + qd * 8;
  short8 qf[2][4];
#pragma unroll
  for (int mi = 0; mi < 2; mi++)
#pragma unroll
    for (int ks = 0; ks < 4; ks++)
      qf[mi][ks] = *(const short8*)(qp + (size_t)mi * 16384 + ks * 32);

  // K frag base: row (kv0 + ni*16 + l16), dh-chunk ks*4+qd
  const unsigned short* kp = kb + kbase + (size_t)l16 * 1024 + qd * 8;
  // V frag base: vt row dh = ni*16 + l16, col kv0 + qd*8
  const unsigned short* vp = vt + vbase + (size_t)l16 * 2048 + qd * 8;

  floatx4 oacc[2][8];
#pragma unroll
  for (int mi = 0; mi < 2; mi++)
#pragma unroll
    for (int ni = 0; ni < 8; ni++) { floatx4 z = {0.f, 0.f, 0.f, 0.f}; oacc[mi][ni] = z; }
  float lsum[2][4];
#pragma unroll
  for (int mi = 0; mi < 2; mi++)
#pragma unroll
    for (int r = 0; r < 4; r++) lsum[mi][r] = 0.f;

  for (int it = 0; it < 64; it++) {
    const int kv0 = it * 32;

    // S = Q K^T (wave: 32 rows x 32 cols)
    floatx4 sacc[2][2];
#pragma unroll
    for (int mi = 0; mi < 2; mi++)
#pragma unroll
      for (int ni = 0; ni < 2; ni++) { floatx4 z = {0.f, 0.f, 0.f, 0.f}; sacc[mi][ni] = z; }
#pragma unroll
    for (int ks = 0; ks < 4; ks++) {
      const short8 k0f = *(const short8*)(kp + (size_t)kv0 * 1024 + ks * 32);
      const short8 k1f = *(const short8*)(kp + (size_t)(kv0 + 16) * 1024 + ks * 32);
#pragma unroll
      for (int mi = 0; mi < 2; mi++) {
        sacc[mi][0] = __builtin_amdgcn_mfma_f32_16x16x32_bf16(qf[mi][ks], k0f, sacc[mi][0], 0, 0, 0);
        sacc[mi][1] = __builtin_amdgcn_mfma_f32_16x16x32_bf16(qf[mi][ks], k1f, sacc[mi][1], 0, 0, 0);
      }
    }

    // P = exp(S/32) -> wave-private LDS rows (C-layout -> A-layout)
#pragma unroll
    for (int mi = 0; mi < 2; mi++)
#pragma unroll
      for (int ni = 0; ni < 2; ni++) {
        const int kvl = ni * 16 + l16;
#pragma unroll
        for (int r = 0; r < 4; r++) {
          const float e = __expf(sacc[mi][ni][r] * 0.03125f);
          lsum[mi][r] += e;
          Ps[(kvl >> 3) * 1024 + (w * 32 + mi * 16 + qd * 4 + r) * 8 + (kvl & 7)] = f2bf(e);
        }
      }

    // O += P V (V fragments direct from global)
    short8 pf[2];
#pragma unroll
    for (int mi = 0; mi < 2; mi++)
      pf[mi] = *(const short8*)&Ps[qd * 1024 + (w * 32 + mi * 16 + l16) * 8];
#pragma unroll
    for (int ni = 0; ni < 8; ni++) {
      const short8 vf = *(const short8*)(vp + (size_t)ni * 32768 + kv0);
#pragma unroll
      for (int mi = 0; mi < 2; mi++)
        oacc[mi][ni] = __builtin_amdgcn_mfma_f32_16x16x32_bf16(pf[mi], vf, oacc[mi][ni], 0, 0, 0);
    }
  }

  // row sums (cols live in the 16 l16 lanes)
  float inv[2][4];
#pragma unroll
  for (int mi = 0; mi < 2; mi++)
#pragma unroll
    for (int r = 0; r < 4; r++) {
      float s = lsum[mi][r];
      s += __shfl_xor(s, 1); s += __shfl_xor(s, 2);
      s += __shfl_xor(s, 4); s += __shfl_xor(s, 8);
      inv[mi][r] = 1.f / s;
    }

#pragma unroll
  for (int mi = 0; mi < 2; mi++)
#pragma unroll
    for (int ni = 0; ni < 8; ni++)
#pragma unroll
      for (int r = 0; r < 4; r++) {
        const int m = w * 32 + mi * 16 + qd * 4 + r;
        const int dh = ni * 16 + l16;
        const float qv = bf2f(qb[qbase + (size_t)m * 1024 + dh]);
        Ob[qbase + (size_t)m * 1024 + dh] = f2bf(qv + oacc[mi][ni][r] * inv[mi][r]);
      }
}

// =====================================================================
// Row LayerNorm over 1024 (bf16 -> bf16)
// =====================================================================
__global__ __launch_bounds__(256) void ln_rows(const unsigned short* __restrict__ X,
                                               const float* __restrict__ g,
                                               const float* __restrict__ bb,
                                               unsigned short* __restrict__ Y) {
  __shared__ float red[8];
  const int row = blockIdx.x, tid = threadIdx.x;
  const int w = tid >> 6, lane = tid & 63;
  const ushortx4 u = ((const ushortx4*)(X + (size_t)row * 1024))[tid];
  float x0 = bf2f(u.x), x1 = bf2f(u.y), x2 = bf2f(u.z), x3 = bf2f(u.w);
  float s = x0 + x1 + x2 + x3;
  float s2 = x0 * x0 + x1 * x1 + x2 * x2 + x3 * x3;
#pragma unroll
  for (int off = 1; off < 64; off <<= 1) { s += __shfl_xor(s, off); s2 += __shfl_xor(s2, off); }
  if (lane == 0) { red[w] = s; red[4 + w] = s2; }
  __syncthreads();
  s = red[0] + red[1] + red[2] + red[3];
  s2 = red[4] + red[5] + red[6] + red[7];
  const float mu = s * (1.f / 1024.f);
  const float rs = rsqrtf(s2 * (1.f / 1024.f) - mu * mu + 1e-5f);
  const floatx4 gv = ((const floatx4*)g)[tid];
  const floatx4 bv = ((const floatx4*)bb)[tid];
  ushortx4 o;
  o.x = f2bf((x0 - mu) * rs * gv.x + bv.x);
  o.y = f2bf((x1 - mu) * rs * gv.y + bv.y);
  o.z = f2bf((x2 - mu) * rs * gv.z + bv.z);
  o.w = f2bf((x3 - mu) * rs * gv.w + bv.w);
  ((ushortx4*)(Y + (size_t)row * 1024))[tid] = o;
}

// =====================================================================
// Row LayerNorm over 1024 (f32 -> f32) for the final output
// =====================================================================
__global__ __launch_bounds__(256) void ln_f32(const float* __restrict__ X,
                                              const float* __restrict__ g,
                                              const float* __restrict__ bb,
                                              float* __restrict__ out) {
  __shared__ float red[8];
  const int row = blockIdx.x, tid = threadIdx.x;
  const int w = tid >> 6, lane = tid & 63;
  const floatx4 xv = ((const floatx4*)(X + (size_t)row * 1024))[tid];
  float x0 = xv.x, x1 = xv.y, x2 = xv.z, x3 = xv.w;
  float s = x0 + x1 + x2 + x3;
  float s2 = x0 * x0 + x1 * x1 + x2 * x2 + x3 * x3;
#pragma unroll
  for (int off = 1; off < 64; off <<= 1) { s += __shfl_xor(s, off); s2 += __shfl_xor(s2, off); }
  if (lane == 0) { red[w] = s; red[4 + w] = s2; }
  __syncthreads();
  s = red[0] + red[1] + red[2] + red[3];
  s2 = red[4] + red[5] + red[6] + red[7];
  const float mu = s * (1.f / 1024.f);
  const float rs = rsqrtf(s2 * (1.f / 1024.f) - mu * mu + 1e-5f);
  const floatx4 gv = ((const floatx4*)g)[tid];
  const floatx4 bv = ((const floatx4*)bb)[tid];
  floatx4 o;
  o.x = (x0 - mu) * rs * gv.x + bv.x;
  o.y = (x1 - mu) * rs * gv.y + bv.y;
  o.z = (x2 - mu) * rs * gv.z + bv.z;
  o.w = (x3 - mu) * rs * gv.w + bv.w;
  ((floatx4*)(out + (size_t)row * 1024))[tid] = o;
}

// =====================================================================
// Host launch
// =====================================================================
extern "C" void kernel_launch(void* const* d_in, const int* in_sizes, int n_in,
                              void* d_out, int out_size, void* d_ws, size_t ws_size,
                              hipStream_t stream) {
  (void)in_sizes; (void)n_in; (void)out_size; (void)ws_size;
  const float* Q  = (const float*)d_in[0];
  const float* K  = (const float*)d_in[1];
  const float* Wq = (const float*)d_in[2];
  const float* bq = (const float*)d_in[3];
  const float* Wk = (const float*)d_in[4];
  const float* bk = (const float*)d_in[5];
  const float* Wv = (const float*)d_in[6];
  const float* bv = (const float*)d_in[7];
  const float* Wo = (const float*)d_in[8];
  const float* bo = (const float*)d_in[9];
  const float* g0 = (const float*)d_in[10];
  const float* b0 = (const float*)d_in[11];
  const float* g1 = (const float*)d_in[12];
  const float* b1 = (const float*)d_in[13];
  float* out = (float*)d_out;

  char* ws = (char*)d_ws;
  const size_t MB = 1u << 20;
  unsigned short* Qb  = (unsigned short*)(ws + 0);         // 16 MB [later: O]
  unsigned short* Kb  = (unsigned short*)(ws + 16 * MB);   // 32 MB [later: X1]
  unsigned short* Wt  = (unsigned short*)(ws + 48 * MB);   // 8 MB stacked Wq|Wk|Wv|Wo (^T)
  unsigned short* qbp = (unsigned short*)(ws + 56 * MB);   // 16 MB
  unsigned short* kbp = (unsigned short*)(ws + 72 * MB);   // 32 MB [later: O2 f32]
  unsigned short* vtp = (unsigned short*)(ws + 104 * MB);  // 32 MB
  unsigned short* O   = Qb;
  unsigned short* X1  = Kb;
  float* O2 = (float*)(ws + 72 * MB);

  unsigned short* Wqt  = Wt;
  unsigned short* Wkvt = Wt + (size_t)1024 * 1024;  // [Wk^T ; Wv^T] = [2048][1024]
  unsigned short* Wot  = Wt + (size_t)3072 * 1024;

  cvt_qk<<<24576, 256, 0, stream>>>(Q, K, Qb, Kb);
  wtrans4<<<dim3(32, 32, 4), dim3(32, 8), 0, stream>>>(Wq, Wk, Wv, Wo, Wt);

  // Q projection -> qbp (bf16 rowmajor), register-direct, XCD m-banded
  gemm_rd<0, 3><<<512, 256, 0, stream>>>(Qb, Wqt, bq, nullptr, qbp);
  // fused K+V projection, register-direct (M=16384, N=2048)
  gemm_kv_rd<<<2048, 256, 0, stream>>>(Kb, Wkvt, bk, bv, kbp, vtp);
  // attention (+ q residual) -> O bf16, barrier-free
  attn<<<512, 256, 0, stream>>>(qbp, kbp, vtp, O);
  // LN0
  ln_rows<<<8192, 256, 0, stream>>>(O, g0, b0, X1);
  // O2 = X1 + relu(X1 @ Wo + bo)  (f32), register-direct
  gemm_rd<2, 3><<<512, 256, 0, stream>>>(X1, Wot, bo, X1, O2);
  // out = LN(O2)
  ln_f32<<<8192, 256, 0, stream>>>(O2, g1, b1, out);
}

// Round 7
// 437.901 us; speedup vs baseline: 1.8280x; 1.8280x over previous
//
#include <hip/hip_runtime.h>
#include <stdint.h>

#define DEVI static __device__ __forceinline__

typedef __attribute__((ext_vector_type(8))) short short8;
typedef __attribute__((ext_vector_type(4))) float floatx4;
typedef __attribute__((ext_vector_type(4))) unsigned short ushortx4;

// ---------- bf16 helpers ----------
DEVI unsigned short f2bf(float f) {
  union { float f; uint32_t u; } v; v.f = f;
  uint32_t r = v.u + 0x7FFFu + ((v.u >> 16) & 1u);
  return (unsigned short)(r >> 16);
}
DEVI float bf2f(unsigned short s) {
  union { uint32_t u; float f; } v; v.u = ((uint32_t)s) << 16;
  return v.f;
}
// f32 -> fp8 e4m3 (OCP), scalar via pack builtin
DEVI unsigned char f2fp8(float f) {
  return (unsigned char)(__builtin_amdgcn_cvt_pk_fp8_f32(f, f, 0, false) & 0xff);
}

// ---------- async global->LDS 16B ----------
DEVI void lds_cp16(void* lds, const void* g) {
  __builtin_amdgcn_global_load_lds(
      (const __attribute__((address_space(1))) uint32_t*)g,
      reinterpret_cast<__attribute__((address_space(3))) uint32_t*>(
          (uint32_t)reinterpret_cast<uintptr_t>(lds)),
      16, 0, 0);
}

// =====================================================================
// Convert: Q (first 8192 blocks) f32->bf16; K (next 16384 blocks) f32->fp8
// =====================================================================
__global__ __launch_bounds__(256) void cvt_qk(const float* __restrict__ Q,
                                              const float* __restrict__ K,
                                              unsigned short* __restrict__ Qb,
                                              unsigned char* __restrict__ Kf8) {
  const int bid = blockIdx.x;
  if (bid < 8192) {
    const size_t i = (size_t)bid * 256 + threadIdx.x;
    const floatx4 v = ((const floatx4*)Q)[i];
    ushortx4 o;
    o.x = f2bf(v.x); o.y = f2bf(v.y); o.z = f2bf(v.z); o.w = f2bf(v.w);
    ((ushortx4*)Qb)[i] = o;
  } else {
    const size_t i = (size_t)(bid - 8192) * 256 + threadIdx.x;
    const floatx4 v = ((const floatx4*)K)[i];
    int p = __builtin_amdgcn_cvt_pk_fp8_f32(v.x, v.y, 0, false);
    p = __builtin_amdgcn_cvt_pk_fp8_f32(v.z, v.w, p, true);
    ((int*)Kf8)[i] = p;
  }
}

// =====================================================================
// Weight transposes. z: 0=Wq(bf16), 1=Wk(fp8), 2=Wv(fp8), 3=Wo(bf16).
// Wt  (bf16 [2048][1024]): Wq^T rows 0..1023, Wo^T rows 1024..2047
// Wt8 (fp8  [2048][1024]): Wk^T rows 0..1023, Wv^T rows 1024..2047
// =====================================================================
__global__ __launch_bounds__(256) void wtrans4(const float* __restrict__ Wq,
                                               const float* __restrict__ Wk,
                                               const float* __restrict__ Wv,
                                               const float* __restrict__ Wo,
                                               unsigned short* __restrict__ Wt,
                                               unsigned char* __restrict__ Wt8) {
  __shared__ float t[32][33];
  const int tx = threadIdx.x, ty = threadIdx.y;
  const int z = blockIdx.z;
  const float* W = (z == 0) ? Wq : (z == 1) ? Wk : (z == 2) ? Wv : Wo;
  const int c0 = blockIdx.x * 32, r0 = blockIdx.y * 32;
#pragma unroll
  for (int i = 0; i < 4; i++)
    t[ty + i * 8][tx] = W[(size_t)(r0 + ty + i * 8) * 1024 + c0 + tx];
  __syncthreads();
  if (z == 0 || z == 3) {
    unsigned short* D = Wt + (z == 0 ? 0 : (size_t)1024 * 1024);
#pragma unroll
    for (int i = 0; i < 4; i++)
      D[(size_t)(c0 + ty + i * 8) * 1024 + r0 + tx] = f2bf(t[tx][ty + i * 8]);
  } else {
    unsigned char* D = Wt8 + (z == 1 ? 0 : (size_t)1024 * 1024);
#pragma unroll
    for (int i = 0; i < 4; i++)
      D[(size_t)(c0 + ty + i * 8) * 1024 + r0 + tx] = f2fp8(t[tx][ty + i * 8]);
  }
}

// =====================================================================
// GEMM 128x128 tile bf16 (Q / Wo): C[8192][1024] = A @ Bt^T + bias
// 512 blocks 1D, XCD m-banded. EPI: 0 = bf16 out; 2 = f32 fused
// O2 = X1 + relu(acc+bias)
// =====================================================================
template <int EPI>
__global__ __launch_bounds__(256, 3) void gemm_bt(
    const unsigned short* __restrict__ A, const unsigned short* __restrict__ Bt,
    const float* __restrict__ bias, const unsigned short* __restrict__ X1,
    void* __restrict__ Cout) {
  __shared__ unsigned short As[2][4][128][8];
  __shared__ unsigned short Bs[2][4][128][8];

  const int tid = threadIdx.x;
  const int lane = tid & 63, w = tid >> 6;
  const int wr = w >> 1, wc = w & 1;
  const int qd = lane >> 4, l16 = lane & 15;
  const int bid = blockIdx.x;
  const int xcd = bid & 7, loc = bid >> 3;
  const int m0 = (xcd * 8 + (loc & 7)) * 128;
  const int n0 = (loc >> 3) * 128;

  floatx4 acc[4][4];
#pragma unroll
  for (int i = 0; i < 4; i++)
#pragma unroll
    for (int j = 0; j < 4; j++) { floatx4 z = {0.f, 0.f, 0.f, 0.f}; acc[i][j] = z; }

  const int prow = tid & 127;
  const unsigned short* aptr = A + (size_t)(m0 + prow) * 1024 + ((tid >> 7) << 3);
  const unsigned short* bptr = Bt + (size_t)(n0 + prow) * 1024 + ((tid >> 7) << 3);
  const int dstoff = tid * 8;

  lds_cp16(&As[0][0][0][0] + dstoff, aptr);
  lds_cp16(&As[0][0][0][0] + dstoff + 2048, aptr + 16);
  lds_cp16(&Bs[0][0][0][0] + dstoff, bptr);
  lds_cp16(&Bs[0][0][0][0] + dstoff + 2048, bptr + 16);

  for (int it = 0; it < 32; it++) {
    __syncthreads();
    if (it < 31) {
      const int nb = (it + 1) & 1, k0 = (it + 1) * 32;
      lds_cp16(&As[nb][0][0][0] + dstoff, aptr + k0);
      lds_cp16(&As[nb][0][0][0] + dstoff + 2048, aptr + k0 + 16);
      lds_cp16(&Bs[nb][0][0][0] + dstoff, bptr + k0);
      lds_cp16(&Bs[nb][0][0][0] + dstoff + 2048, bptr + k0 + 16);
    }
    const int cur = it & 1;
    short8 af[4], bf[4];
#pragma unroll
    for (int mi = 0; mi < 4; mi++)
      af[mi] = *(const short8*)&As[cur][qd][wr * 64 + mi * 16 + l16][0];
#pragma unroll
    for (int ni = 0; ni < 4; ni++)
      bf[ni] = *(const short8*)&Bs[cur][qd][wc * 64 + ni * 16 + l16][0];
#pragma unroll
    for (int mi = 0; mi < 4; mi++)
#pragma unroll
      for (int ni = 0; ni < 4; ni++)
        acc[mi][ni] =
            __builtin_amdgcn_mfma_f32_16x16x32_bf16(af[mi], bf[ni], acc[mi][ni], 0, 0, 0);
  }

#pragma unroll
  for (int mi = 0; mi < 4; mi++) {
#pragma unroll
    for (int ni = 0; ni < 4; ni++) {
      const int row = m0 + wr * 64 + mi * 16 + qd * 4;
      const int col = n0 + wc * 64 + ni * 16 + l16;
      const float bv = bias[col];
      if constexpr (EPI == 0) {
        unsigned short* C = (unsigned short*)Cout;
#pragma unroll
        for (int r = 0; r < 4; r++)
          C[(size_t)(row + r) * 1024 + col] = f2bf(acc[mi][ni][r] + bv);
      } else {
        float* C = (float*)Cout;
#pragma unroll
        for (int r = 0; r < 4; r++) {
          const float x1 = bf2f(X1[(size_t)(row + r) * 1024 + col]);
          C[(size_t)(row + r) * 1024 + col] = x1 + fmaxf(acc[mi][ni][r] + bv, 0.f);
        }
      }
    }
  }
}

// =====================================================================
// KV GEMM in FP8 e4m3: C[16384][2048] = Kf8 @ Wt8^T + bias
// 128x128 tile, 4 waves of 64x64, BK=64 (32 MFMA/wave per barrier),
// mfma_f32_16x16x32_fp8_fp8 (same k=quad*8+j geometry as bf16, 8B/lane).
// LDS [buf][c2=k/16][row][16 fp8] (16B global-contiguous units).
// XCD m-banded: xcd owns 16 m-tiles (A-band 2MB + B 2MB -> L2-resident).
// cols <1024 -> kbp bf16 rowmajor (+bk); cols >=1024 -> vt[b][h][dh][nk] (+bv)
// =====================================================================
__global__ __launch_bounds__(256, 3) void gemm_kv_f8(
    const unsigned char* __restrict__ A, const unsigned char* __restrict__ Bt,
    const float* __restrict__ biasK, const float* __restrict__ biasV,
    unsigned short* __restrict__ CK, unsigned short* __restrict__ CV) {
  __shared__ unsigned char As[2][4][128][16];  // 16 KB total
  __shared__ unsigned char Bs[2][4][128][16];  // 16 KB total

  const int tid = threadIdx.x;
  const int lane = tid & 63, w = tid >> 6;
  const int wr = w >> 1, wc = w & 1;
  const int qd = lane >> 4, l16 = lane & 15;
  const int bid = blockIdx.x;
  const int xcd = bid & 7, loc = bid >> 3;
  const int m0 = (xcd * 16 + (loc & 15)) * 128;  // 128 m-tiles
  const int n0 = (loc >> 4) * 128;               // 16 n-tiles

  floatx4 acc[4][4];
#pragma unroll
  for (int i = 0; i < 4; i++)
#pragma unroll
    for (int j = 0; j < 4; j++) { floatx4 z = {0.f, 0.f, 0.f, 0.f}; acc[i][j] = z; }

  // staging: unit = (c2, row) 16B; thread covers c2=sc & c2=sc+2 at row srow
  const int srow = tid & 127, sc = tid >> 7;  // sc in {0,1}
  const unsigned char* aptr = A + (size_t)(m0 + srow) * 1024 + sc * 16;
  const unsigned char* bptr = Bt + (size_t)(n0 + srow) * 1024 + sc * 16;
  unsigned char* dA = &As[0][sc][srow][0];
  unsigned char* dB = &Bs[0][sc][srow][0];

  lds_cp16(dA, aptr);
  lds_cp16(dA + 4096, aptr + 32);
  lds_cp16(dB, bptr);
  lds_cp16(dB + 4096, bptr + 32);

  for (int it = 0; it < 16; it++) {
    __syncthreads();
    if (it < 15) {
      const int nb = (it + 1) & 1, k0 = (it + 1) * 64;
      lds_cp16(dA + nb * 8192, aptr + k0);
      lds_cp16(dA + nb * 8192 + 4096, aptr + k0 + 32);
      lds_cp16(dB + nb * 8192, bptr + k0);
      lds_cp16(dB + nb * 8192 + 4096, bptr + k0 + 32);
    }
    const int cur = it & 1;
    // fragment: k = ks*32 + qd*8 + j -> c2 = ks*2 + (qd>>1), byte off (qd&1)*8
    const int coff = (qd & 1) * 8, chi = qd >> 1;
    long a8[4][2], b8[4][2];
#pragma unroll
    for (int mi = 0; mi < 4; mi++) {
      const int row = wr * 64 + mi * 16 + l16;
      a8[mi][0] = *(const long*)&As[cur][chi][row][coff];
      a8[mi][1] = *(const long*)&As[cur][2 + chi][row][coff];
    }
#pragma unroll
    for (int ni = 0; ni < 4; ni++) {
      const int row = wc * 64 + ni * 16 + l16;
      b8[ni][0] = *(const long*)&Bs[cur][chi][row][coff];
      b8[ni][1] = *(const long*)&Bs[cur][2 + chi][row][coff];
    }
#pragma unroll
    for (int mi = 0; mi < 4; mi++)
#pragma unroll
      for (int ni = 0; ni < 4; ni++)
        acc[mi][ni] = __builtin_amdgcn_mfma_f32_16x16x32_fp8_fp8(
            a8[mi][0], b8[ni][0], acc[mi][ni], 0, 0, 0);
#pragma unroll
    for (int mi = 0; mi < 4; mi++)
#pragma unroll
      for (int ni = 0; ni < 4; ni++)
        acc[mi][ni] = __builtin_amdgcn_mfma_f32_16x16x32_fp8_fp8(
            a8[mi][1], b8[ni][1], acc[mi][ni], 0, 0, 0);
  }

#pragma unroll
  for (int mi = 0; mi < 4; mi++) {
#pragma unroll
    for (int ni = 0; ni < 4; ni++) {
      const int row = m0 + wr * 64 + mi * 16 + qd * 4;
      const int col = n0 + wc * 64 + ni * 16 + l16;
      if (col < 1024) {  // K half (wave-uniform: n0 multiple of 128)
        const float bv = biasK[col];
#pragma unroll
        for (int r = 0; r < 4; r++)
          CK[(size_t)(row + r) * 1024 + col] = f2bf(acc[mi][ni][r] + bv);
      } else {  // V half -> vt[b][h][dh][nk]
        const int vc = col - 1024;
        const float bv = biasV[vc];
        const int bb = row >> 11, nk = row & 2047;
        const int hh = vc >> 7, dh = vc & 127;
        ushortx4 pk;
        pk.x = f2bf(acc[mi][ni][0] + bv);
        pk.y = f2bf(acc[mi][ni][1] + bv);
        pk.z = f2bf(acc[mi][ni][2] + bv);
        pk.w = f2bf(acc[mi][ni][3] + bv);
        *(ushortx4*)&CV[(size_t)((bb * 8 + hh) * 128 + dh) * 2048 + nk] = pk;
      }
    }
  }
}

// =====================================================================
// Flash attention (R5-proven): 128 q-rows/block, BN=32 KV dbuf, single
// barrier/iter, Ps aliased over Qs, XCD-swizzled grid (bid%8 = b).
// =====================================================================
__global__ __launch_bounds__(256, 2) void attn(
    const unsigned short* __restrict__ qb, const unsigned short* __restrict__ kb,
    const unsigned short* __restrict__ vt, unsigned short* __restrict__ Ob) {
  __shared__ unsigned short smem[32768];

  const int tid = threadIdx.x;
  const int lane = tid & 63, w = tid >> 6;
  const int qd = lane >> 4, l16 = lane & 15;
  const int bid = blockIdx.x;
  const int qt = bid >> 6, bh = bid & 63;
  const int h = bh >> 3, b = bh & 7;
  const int m0 = qt * 128;

  const size_t qbase = ((size_t)(b * 1024 + m0)) * 1024 + h * 128;
  const size_t kbase = ((size_t)(b * 2048)) * 1024 + h * 128;
  const size_t vbase = ((size_t)((b * 8 + h) * 128)) * 2048;

#pragma unroll
  for (int i = 0; i < 8; i++) {
    const int p = i * 256 + tid;
    const int row = p & 127, c = p >> 7;
    lds_cp16(&smem[c * 1024 + row * 8], qb + qbase + (size_t)row * 1024 + c * 8);
  }
#pragma unroll
  for (int i = 0; i < 2; i++) {
    const int p = i * 256 + tid;
    const int kr = p & 31, kc = p >> 5;
    lds_cp16(&smem[16384 + kc * 256 + kr * 8], kb + kbase + (size_t)kr * 1024 + kc * 8);
    const int dh = p & 127, vc = p >> 7;
    lds_cp16(&smem[24576 + vc * 1024 + dh * 8], vt + vbase + (size_t)dh * 2048 + vc * 8);
  }
  __syncthreads();

  short8 qf[2][4];
#pragma unroll
  for (int mi = 0; mi < 2; mi++)
#pragma unroll
    for (int ks = 0; ks < 4; ks++)
      qf[mi][ks] =
          *(const short8*)&smem[(ks * 4 + qd) * 1024 + ((w * 2 + mi) * 16 + l16) * 8];
  __syncthreads();

  floatx4 oacc[2][8];
#pragma unroll
  for (int mi = 0; mi < 2; mi++)
#pragma unroll
    for (int ni = 0; ni < 8; ni++) { floatx4 z = {0.f, 0.f, 0.f, 0.f}; oacc[mi][ni] = z; }
  float lsum[2][4];
#pragma unroll
  for (int mi = 0; mi < 2; mi++)
#pragma unroll
    for (int r = 0; r < 4; r++) lsum[mi][r] = 0.f;

  for (int it = 0; it < 64; it++) {
    if (it) __syncthreads();
    if (it + 1 < 64) {
      const int nb = (it + 1) & 1, kv0 = (it + 1) * 32;
#pragma unroll
      for (int i = 0; i < 2; i++) {
        const int p = i * 256 + tid;
        const int kr = p & 31, kc = p >> 5;
        lds_cp16(&smem[16384 + nb * 4096 + kc * 256 + kr * 8],
                 kb + kbase + (size_t)(kv0 + kr) * 1024 + kc * 8);
        const int dh = p & 127, vc = p >> 7;
        lds_cp16(&smem[24576 + nb * 4096 + vc * 1024 + dh * 8],
                 vt + vbase + (size_t)dh * 2048 + kv0 + vc * 8);
      }
    }
    const int cur = it & 1;

    floatx4 sacc[2][2];
#pragma unroll
    for (int mi = 0; mi < 2; mi++)
#pragma unroll
      for (int ni = 0; ni < 2; ni++) { floatx4 z = {0.f, 0.f, 0.f, 0.f}; sacc[mi][ni] = z; }
#pragma unroll
    for (int ks = 0; ks < 4; ks++) {
      short8 b0 = *(const short8*)&smem[16384 + cur * 4096 + (ks * 4 + qd) * 256 + l16 * 8];
      short8 b1 =
          *(const short8*)&smem[16384 + cur * 4096 + (ks * 4 + qd) * 256 + (16 + l16) * 8];
#pragma unroll
      for (int mi = 0; mi < 2; mi++) {
        sacc[mi][0] = __builtin_amdgcn_mfma_f32_16x16x32_bf16(qf[mi][ks], b0, sacc[mi][0], 0, 0, 0);
        sacc[mi][1] = __builtin_amdgcn_mfma_f32_16x16x32_bf16(qf[mi][ks], b1, sacc[mi][1], 0, 0, 0);
      }
    }

#pragma unroll
    for (int mi = 0; mi < 2; mi++)
#pragma unroll
      for (int ni = 0; ni < 2; ni++) {
        const int kvl = ni * 16 + l16;
#pragma unroll
        for (int r = 0; r < 4; r++) {
          const float e = __expf(sacc[mi][ni][r] * 0.03125f);
          lsum[mi][r] += e;
          smem[(kvl >> 3) * 1024 + ((w * 2 + mi) * 16 + qd * 4 + r) * 8 + (kvl & 7)] = f2bf(e);
        }
      }

    short8 pf[2];
#pragma unroll
    for (int mi = 0; mi < 2; mi++)
      pf[mi] = *(const short8*)&smem[qd * 1024 + ((w * 2 + mi) * 16 + l16) * 8];
#pragma unroll
    for (int ni = 0; ni < 8; ni++) {
      const short8 vf = *(const short8*)&smem[24576 + cur * 4096 + qd * 1024 + (ni * 16 + l16) * 8];
#pragma unroll
      for (int mi = 0; mi < 2; mi++)
        oacc[mi][ni] = __builtin_amdgcn_mfma_f32_16x16x32_bf16(pf[mi], vf, oacc[mi][ni], 0, 0, 0);
    }
  }

  float inv[2][4];
#pragma unroll
  for (int mi = 0; mi < 2; mi++)
#pragma unroll
    for (int r = 0; r < 4; r++) {
      float s = lsum[mi][r];
      s += __shfl_xor(s, 1); s += __shfl_xor(s, 2);
      s += __shfl_xor(s, 4); s += __shfl_xor(s, 8);
      inv[mi][r] = 1.f / s;
    }

#pragma unroll
  for (int mi = 0; mi < 2; mi++)
#pragma unroll
    for (int ni = 0; ni < 8; ni++)
#pragma unroll
      for (int r = 0; r < 4; r++) {
        const int m = (w * 2 + mi) * 16 + qd * 4 + r;
        const int dh = ni * 16 + l16;
        const float qv = bf2f(qb[qbase + (size_t)m * 1024 + dh]);
        Ob[qbase + (size_t)m * 1024 + dh] = f2bf(qv + oacc[mi][ni][r] * inv[mi][r]);
      }
}

// =====================================================================
// Row LayerNorm over 1024 (bf16 -> bf16)
// =====================================================================
__global__ __launch_bounds__(256) void ln_rows(const unsigned short* __restrict__ X,
                                               const float* __restrict__ g,
                                               const float* __restrict__ bb,
                                               unsigned short* __restrict__ Y) {
  __shared__ float red[8];
  const int row = blockIdx.x, tid = threadIdx.x;
  const int w = tid >> 6, lane = tid & 63;
  const ushortx4 u = ((const ushortx4*)(X + (size_t)row * 1024))[tid];
  float x0 = bf2f(u.x), x1 = bf2f(u.y), x2 = bf2f(u.z), x3 = bf2f(u.w);
  float s = x0 + x1 + x2 + x3;
  float s2 = x0 * x0 + x1 * x1 + x2 * x2 + x3 * x3;
#pragma unroll
  for (int off = 1; off < 64; off <<= 1) { s += __shfl_xor(s, off); s2 += __shfl_xor(s2, off); }
  if (lane == 0) { red[w] = s; red[4 + w] = s2; }
  __syncthreads();
  s = red[0] + red[1] + red[2] + red[3];
  s2 = red[4] + red[5] + red[6] + red[7];
  const float mu = s * (1.f / 1024.f);
  const float rs = rsqrtf(s2 * (1.f / 1024.f) - mu * mu + 1e-5f);
  const floatx4 gv = ((const floatx4*)g)[tid];
  const floatx4 bv = ((const floatx4*)bb)[tid];
  ushortx4 o;
  o.x = f2bf((x0 - mu) * rs * gv.x + bv.x);
  o.y = f2bf((x1 - mu) * rs * gv.y + bv.y);
  o.z = f2bf((x2 - mu) * rs * gv.z + bv.z);
  o.w = f2bf((x3 - mu) * rs * gv.w + bv.w);
  ((ushortx4*)(Y + (size_t)row * 1024))[tid] = o;
}

// =====================================================================
// Row LayerNorm over 1024 (f32 -> f32) for the final output
// =====================================================================
__global__ __launch_bounds__(256) void ln_f32(const float* __restrict__ X,
                                              const float* __restrict__ g,
                                              const float* __restrict__ bb,
                                              float* __restrict__ out) {
  __shared__ float red[8];
  const int row = blockIdx.x, tid = threadIdx.x;
  const int w = tid >> 6, lane = tid & 63;
  const floatx4 xv = ((const floatx4*)(X + (size_t)row * 1024))[tid];
  float x0 = xv.x, x1 = xv.y, x2 = xv.z, x3 = xv.w;
  float s = x0 + x1 + x2 + x3;
  float s2 = x0 * x0 + x1 * x1 + x2 * x2 + x3 * x3;
#pragma unroll
  for (int off = 1; off < 64; off <<= 1) { s += __shfl_xor(s, off); s2 += __shfl_xor(s2, off); }
  if (lane == 0) { red[w] = s; red[4 + w] = s2; }
  __syncthreads();
  s = red[0] + red[1] + red[2] + red[3];
  s2 = red[4] + red[5] + red[6] + red[7];
  const float mu = s * (1.f / 1024.f);
  const float rs = rsqrtf(s2 * (1.f / 1024.f) - mu * mu + 1e-5f);
  const floatx4 gv = ((const floatx4*)g)[tid];
  const floatx4 bv = ((const floatx4*)bb)[tid];
  floatx4 o;
  o.x = (x0 - mu) * rs * gv.x + bv.x;
  o.y = (x1 - mu) * rs * gv.y + bv.y;
  o.z = (x2 - mu) * rs * gv.z + bv.z;
  o.w = (x3 - mu) * rs * gv.w + bv.w;
  ((floatx4*)(out + (size_t)row * 1024))[tid] = o;
}

// =====================================================================
// Host launch
// =====================================================================
extern "C" void kernel_launch(void* const* d_in, const int* in_sizes, int n_in,
                              void* d_out, int out_size, void* d_ws, size_t ws_size,
                              hipStream_t stream) {
  (void)in_sizes; (void)n_in; (void)out_size; (void)ws_size;
  const float* Q  = (const float*)d_in[0];
  const float* K  = (const float*)d_in[1];
  const float* Wq = (const float*)d_in[2];
  const float* bq = (const float*)d_in[3];
  const float* Wk = (const float*)d_in[4];
  const float* bk = (const float*)d_in[5];
  const float* Wv = (const float*)d_in[6];
  const float* bv = (const float*)d_in[7];
  const float* Wo = (const float*)d_in[8];
  const float* bo = (const float*)d_in[9];
  const float* g0 = (const float*)d_in[10];
  const float* b0 = (const float*)d_in[11];
  const float* g1 = (const float*)d_in[12];
  const float* b1 = (const float*)d_in[13];
  float* out = (float*)d_out;

  char* ws = (char*)d_ws;
  const size_t MB = 1u << 20;
  unsigned short* Qb  = (unsigned short*)(ws + 0);         // 16 MB [later: O bf16]
  unsigned short* X1  = (unsigned short*)(ws + 16 * MB);   // 16 MB
  unsigned short* Wt  = (unsigned short*)(ws + 32 * MB);   // 4 MB bf16 [Wq^T;Wo^T]
  unsigned char*  Wt8 = (unsigned char*)(ws + 36 * MB);    // 2 MB fp8 [Wk^T;Wv^T]
  unsigned char*  Kf8 = (unsigned char*)(ws + 38 * MB);    // 16 MB
  unsigned short* qbp = (unsigned short*)(ws + 54 * MB);   // 16 MB
  unsigned short* kbp = (unsigned short*)(ws + 70 * MB);   // 32 MB [later: O2 f32]
  unsigned short* vtp = (unsigned short*)(ws + 102 * MB);  // 32 MB
  unsigned short* O   = Qb;
  float* O2 = (float*)(ws + 70 * MB);

  unsigned short* Wqt = Wt;
  unsigned short* Wot = Wt + (size_t)1024 * 1024;

  cvt_qk<<<24576, 256, 0, stream>>>(Q, K, Qb, Kf8);
  wtrans4<<<dim3(32, 32, 4), dim3(32, 8), 0, stream>>>(Wq, Wk, Wv, Wo, Wt, Wt8);

  // Q projection -> qbp (bf16 rowmajor), 128x128 bf16, XCD m-banded
  gemm_bt<0><<<512, 256, 0, stream>>>(Qb, Wqt, bq, nullptr, qbp);
  // fused K+V projection in FP8 (M=16384, N=2048), XCD m-banded
  gemm_kv_f8<<<2048, 256, 0, stream>>>(Kf8, Wt8, bk, bv, kbp, vtp);
  // attention (+ q residual) -> O bf16
  attn<<<512, 256, 0, stream>>>(qbp, kbp, vtp, O);
  // LN0
  ln_rows<<<8192, 256, 0, stream>>>(O, g0, b0, X1);
  // O2 = X1 + relu(X1 @ Wo + bo)  (f32), XCD m-banded
  gemm_bt<2><<<512, 256, 0, stream>>>(X1, Wot, bo, X1, O2);
  // out = LN(O2)
  ln_f32<<<8192, 256, 0, stream>>>(O2, g1, b1, out);
}

// Round 8
// 430.883 us; speedup vs baseline: 1.8578x; 1.0163x over previous
//
#include <hip/hip_runtime.h>
#include <stdint.h>

#define DEVI static __device__ __forceinline__

typedef __attribute__((ext_vector_type(8))) short short8;
typedef __attribute__((ext_vector_type(4))) float floatx4;
typedef __attribute__((ext_vector_type(4))) unsigned short ushortx4;

// ---------- bf16 helpers ----------
DEVI unsigned short f2bf(float f) {
  union { float f; uint32_t u; } v; v.f = f;
  uint32_t r = v.u + 0x7FFFu + ((v.u >> 16) & 1u);
  return (unsigned short)(r >> 16);
}
DEVI unsigned short f2bf_trunc(float f) {
  union { float f; uint32_t u; } v; v.f = f;
  return (unsigned short)(v.u >> 16);
}
DEVI float bf2f(unsigned short s) {
  union { uint32_t u; float f; } v; v.u = ((uint32_t)s) << 16;
  return v.f;
}
DEVI uint32_t fbits(float f) {
  union { float f; uint32_t u; } v; v.f = f;
  return v.u;
}
// f32 -> fp8 e4m3 (OCP)
DEVI unsigned char f2fp8(float f) {
  return (unsigned char)(__builtin_amdgcn_cvt_pk_fp8_f32(f, f, 0, false) & 0xff);
}

// ---------- async global->LDS 16B ----------
DEVI void lds_cp16(void* lds, const void* g) {
  __builtin_amdgcn_global_load_lds(
      (const __attribute__((address_space(1))) uint32_t*)g,
      reinterpret_cast<__attribute__((address_space(3))) uint32_t*>(
          (uint32_t)reinterpret_cast<uintptr_t>(lds)),
      16, 0, 0);
}

// =====================================================================
// Convert: Q (first 8192 blocks) f32->bf16; K (next 16384 blocks) f32->fp8
// =====================================================================
__global__ __launch_bounds__(256) void cvt_qk(const float* __restrict__ Q,
                                              const float* __restrict__ K,
                                              unsigned short* __restrict__ Qb,
                                              unsigned char* __restrict__ Kf8) {
  const int bid = blockIdx.x;
  if (bid < 8192) {
    const size_t i = (size_t)bid * 256 + threadIdx.x;
    const floatx4 v = ((const floatx4*)Q)[i];
    ushortx4 o;
    o.x = f2bf(v.x); o.y = f2bf(v.y); o.z = f2bf(v.z); o.w = f2bf(v.w);
    ((ushortx4*)Qb)[i] = o;
  } else {
    const size_t i = (size_t)(bid - 8192) * 256 + threadIdx.x;
    const floatx4 v = ((const floatx4*)K)[i];
    int p = __builtin_amdgcn_cvt_pk_fp8_f32(v.x, v.y, 0, false);
    p = __builtin_amdgcn_cvt_pk_fp8_f32(v.z, v.w, p, true);
    ((int*)Kf8)[i] = p;
  }
}

// =====================================================================
// Weight transposes. z: 0=Wq(bf16), 1=Wk(fp8), 2=Wv(fp8), 3=Wo(bf16).
// =====================================================================
__global__ __launch_bounds__(256) void wtrans4(const float* __restrict__ Wq,
                                               const float* __restrict__ Wk,
                                               const float* __restrict__ Wv,
                                               const float* __restrict__ Wo,
                                               unsigned short* __restrict__ Wt,
                                               unsigned char* __restrict__ Wt8) {
  __shared__ float t[32][33];
  const int tx = threadIdx.x, ty = threadIdx.y;
  const int z = blockIdx.z;
  const float* W = (z == 0) ? Wq : (z == 1) ? Wk : (z == 2) ? Wv : Wo;
  const int c0 = blockIdx.x * 32, r0 = blockIdx.y * 32;
#pragma unroll
  for (int i = 0; i < 4; i++)
    t[ty + i * 8][tx] = W[(size_t)(r0 + ty + i * 8) * 1024 + c0 + tx];
  __syncthreads();
  if (z == 0 || z == 3) {
    unsigned short* D = Wt + (z == 0 ? 0 : (size_t)1024 * 1024);
#pragma unroll
    for (int i = 0; i < 4; i++)
      D[(size_t)(c0 + ty + i * 8) * 1024 + r0 + tx] = f2bf(t[tx][ty + i * 8]);
  } else {
    unsigned char* D = Wt8 + (z == 1 ? 0 : (size_t)1024 * 1024);
#pragma unroll
    for (int i = 0; i < 4; i++)
      D[(size_t)(c0 + ty + i * 8) * 1024 + r0 + tx] = f2fp8(t[tx][ty + i * 8]);
  }
}

// =====================================================================
// GEMM 128x128 tile bf16 (Q / Wo): C[8192][1024] = A @ Bt^T + bias
// XCD m-banded. EPI: 0 = bf16 out; 2 = f32 fused O2 = X1 + relu(acc+bias)
// =====================================================================
template <int EPI>
__global__ __launch_bounds__(256, 3) void gemm_bt(
    const unsigned short* __restrict__ A, const unsigned short* __restrict__ Bt,
    const float* __restrict__ bias, const unsigned short* __restrict__ X1,
    void* __restrict__ Cout) {
  __shared__ unsigned short As[2][4][128][8];
  __shared__ unsigned short Bs[2][4][128][8];

  const int tid = threadIdx.x;
  const int lane = tid & 63, w = tid >> 6;
  const int wr = w >> 1, wc = w & 1;
  const int qd = lane >> 4, l16 = lane & 15;
  const int bid = blockIdx.x;
  const int xcd = bid & 7, loc = bid >> 3;
  const int m0 = (xcd * 8 + (loc & 7)) * 128;
  const int n0 = (loc >> 3) * 128;

  floatx4 acc[4][4];
#pragma unroll
  for (int i = 0; i < 4; i++)
#pragma unroll
    for (int j = 0; j < 4; j++) { floatx4 z = {0.f, 0.f, 0.f, 0.f}; acc[i][j] = z; }

  const int prow = tid & 127;
  const unsigned short* aptr = A + (size_t)(m0 + prow) * 1024 + ((tid >> 7) << 3);
  const unsigned short* bptr = Bt + (size_t)(n0 + prow) * 1024 + ((tid >> 7) << 3);
  const int dstoff = tid * 8;

  lds_cp16(&As[0][0][0][0] + dstoff, aptr);
  lds_cp16(&As[0][0][0][0] + dstoff + 2048, aptr + 16);
  lds_cp16(&Bs[0][0][0][0] + dstoff, bptr);
  lds_cp16(&Bs[0][0][0][0] + dstoff + 2048, bptr + 16);

  for (int it = 0; it < 32; it++) {
    __syncthreads();
    if (it < 31) {
      const int nb = (it + 1) & 1, k0 = (it + 1) * 32;
      lds_cp16(&As[nb][0][0][0] + dstoff, aptr + k0);
      lds_cp16(&As[nb][0][0][0] + dstoff + 2048, aptr + k0 + 16);
      lds_cp16(&Bs[nb][0][0][0] + dstoff, bptr + k0);
      lds_cp16(&Bs[nb][0][0][0] + dstoff + 2048, bptr + k0 + 16);
    }
    const int cur = it & 1;
    short8 af[4], bf[4];
#pragma unroll
    for (int mi = 0; mi < 4; mi++)
      af[mi] = *(const short8*)&As[cur][qd][wr * 64 + mi * 16 + l16][0];
#pragma unroll
    for (int ni = 0; ni < 4; ni++)
      bf[ni] = *(const short8*)&Bs[cur][qd][wc * 64 + ni * 16 + l16][0];
#pragma unroll
    for (int mi = 0; mi < 4; mi++)
#pragma unroll
      for (int ni = 0; ni < 4; ni++)
        acc[mi][ni] =
            __builtin_amdgcn_mfma_f32_16x16x32_bf16(af[mi], bf[ni], acc[mi][ni], 0, 0, 0);
  }

#pragma unroll
  for (int mi = 0; mi < 4; mi++) {
#pragma unroll
    for (int ni = 0; ni < 4; ni++) {
      const int row = m0 + wr * 64 + mi * 16 + qd * 4;
      const int col = n0 + wc * 64 + ni * 16 + l16;
      const float bv = bias[col];
      if constexpr (EPI == 0) {
        unsigned short* C = (unsigned short*)Cout;
#pragma unroll
        for (int r = 0; r < 4; r++)
          C[(size_t)(row + r) * 1024 + col] = f2bf(acc[mi][ni][r] + bv);
      } else {
        float* C = (float*)Cout;
#pragma unroll
        for (int r = 0; r < 4; r++) {
          const float x1 = bf2f(X1[(size_t)(row + r) * 1024 + col]);
          C[(size_t)(row + r) * 1024 + col] = x1 + fmaxf(acc[mi][ni][r] + bv, 0.f);
        }
      }
    }
  }
}

// =====================================================================
// KV GEMM in FP8 e4m3 (R7-proven): C[16384][2048] = Kf8 @ Wt8^T + bias
// =====================================================================
__global__ __launch_bounds__(256, 3) void gemm_kv_f8(
    const unsigned char* __restrict__ A, const unsigned char* __restrict__ Bt,
    const float* __restrict__ biasK, const float* __restrict__ biasV,
    unsigned short* __restrict__ CK, unsigned short* __restrict__ CV) {
  __shared__ unsigned char As[2][4][128][16];
  __shared__ unsigned char Bs[2][4][128][16];

  const int tid = threadIdx.x;
  const int lane = tid & 63, w = tid >> 6;
  const int wr = w >> 1, wc = w & 1;
  const int qd = lane >> 4, l16 = lane & 15;
  const int bid = blockIdx.x;
  const int xcd = bid & 7, loc = bid >> 3;
  const int m0 = (xcd * 16 + (loc & 15)) * 128;
  const int n0 = (loc >> 4) * 128;

  floatx4 acc[4][4];
#pragma unroll
  for (int i = 0; i < 4; i++)
#pragma unroll
    for (int j = 0; j < 4; j++) { floatx4 z = {0.f, 0.f, 0.f, 0.f}; acc[i][j] = z; }

  const int srow = tid & 127, sc = tid >> 7;
  const unsigned char* aptr = A + (size_t)(m0 + srow) * 1024 + sc * 16;
  const unsigned char* bptr = Bt + (size_t)(n0 + srow) * 1024 + sc * 16;
  unsigned char* dA = &As[0][sc][srow][0];
  unsigned char* dB = &Bs[0][sc][srow][0];

  lds_cp16(dA, aptr);
  lds_cp16(dA + 4096, aptr + 32);
  lds_cp16(dB, bptr);
  lds_cp16(dB + 4096, bptr + 32);

  for (int it = 0; it < 16; it++) {
    __syncthreads();
    if (it < 15) {
      const int nb = (it + 1) & 1, k0 = (it + 1) * 64;
      lds_cp16(dA + nb * 8192, aptr + k0);
      lds_cp16(dA + nb * 8192 + 4096, aptr + k0 + 32);
      lds_cp16(dB + nb * 8192, bptr + k0);
      lds_cp16(dB + nb * 8192 + 4096, bptr + k0 + 32);
    }
    const int cur = it & 1;
    const int coff = (qd & 1) * 8, chi = qd >> 1;
    long a8[4][2], b8[4][2];
#pragma unroll
    for (int mi = 0; mi < 4; mi++) {
      const int row = wr * 64 + mi * 16 + l16;
      a8[mi][0] = *(const long*)&As[cur][chi][row][coff];
      a8[mi][1] = *(const long*)&As[cur][2 + chi][row][coff];
    }
#pragma unroll
    for (int ni = 0; ni < 4; ni++) {
      const int row = wc * 64 + ni * 16 + l16;
      b8[ni][0] = *(const long*)&Bs[cur][chi][row][coff];
      b8[ni][1] = *(const long*)&Bs[cur][2 + chi][row][coff];
    }
#pragma unroll
    for (int mi = 0; mi < 4; mi++)
#pragma unroll
      for (int ni = 0; ni < 4; ni++)
        acc[mi][ni] = __builtin_amdgcn_mfma_f32_16x16x32_fp8_fp8(
            a8[mi][0], b8[ni][0], acc[mi][ni], 0, 0, 0);
#pragma unroll
    for (int mi = 0; mi < 4; mi++)
#pragma unroll
      for (int ni = 0; ni < 4; ni++)
        acc[mi][ni] = __builtin_amdgcn_mfma_f32_16x16x32_fp8_fp8(
            a8[mi][1], b8[ni][1], acc[mi][ni], 0, 0, 0);
  }

#pragma unroll
  for (int mi = 0; mi < 4; mi++) {
#pragma unroll
    for (int ni = 0; ni < 4; ni++) {
      const int row = m0 + wr * 64 + mi * 16 + qd * 4;
      const int col = n0 + wc * 64 + ni * 16 + l16;
      if (col < 1024) {
        const float bv = biasK[col];
#pragma unroll
        for (int r = 0; r < 4; r++)
          CK[(size_t)(row + r) * 1024 + col] = f2bf(acc[mi][ni][r] + bv);
      } else {
        const int vc = col - 1024;
        const float bv = biasV[vc];
        const int bb = row >> 11, nk = row & 2047;
        const int hh = vc >> 7, dh = vc & 127;
        ushortx4 pk;
        pk.x = f2bf(acc[mi][ni][0] + bv);
        pk.y = f2bf(acc[mi][ni][1] + bv);
        pk.z = f2bf(acc[mi][ni][2] + bv);
        pk.w = f2bf(acc[mi][ni][3] + bv);
        *(ushortx4*)&CV[(size_t)((bb * 8 + hh) * 128 + dh) * 2048 + nk] = pk;
      }
    }
  }
}

// =====================================================================
// Flash attention v3 — transposed-S formulation, no P LDS round-trip.
// S^T = K·Q^T (C-layout: q in l16, kv in quad/reg); P^T B-frags built via
// ds_bpermute quad-redistribution; O^T = V^T·P^T; O^T transposed back
// once per block through an XOR-swizzled LDS buffer. 32 KB LDS, 3 blk/CU.
// Grid: bid%8 = b (XCD K/V locality). 128 q-rows/block, BN=32 dbuf.
// =====================================================================
__global__ __launch_bounds__(256, 3) void attn(
    const unsigned short* __restrict__ qb, const unsigned short* __restrict__ kb,
    const unsigned short* __restrict__ vt, unsigned short* __restrict__ Ob) {
  __shared__ unsigned short smem[16384];  // 32 KB

  const int tid = threadIdx.x;
  const int lane = tid & 63, w = tid >> 6;
  const int qd = lane >> 4, l16 = lane & 15;
  const int bid = blockIdx.x;
  const int qt = bid >> 6, bh = bid & 63;
  const int h = bh >> 3, b = bh & 7;
  const int m0 = qt * 128;

  const size_t qbase = ((size_t)(b * 1024 + m0)) * 1024 + h * 128;
  const size_t kbase = ((size_t)(b * 2048)) * 1024 + h * 128;
  const size_t vbase = ((size_t)((b * 8 + h) * 128)) * 2048;

  // ---- stage Q transiently (all 32 KB), extract qf, release ----
#pragma unroll
  for (int i = 0; i < 8; i++) {
    const int p = i * 256 + tid;
    const int row = p & 127, c = p >> 7;
    lds_cp16(&smem[c * 1024 + row * 8], qb + qbase + (size_t)row * 1024 + c * 8);
  }
  __syncthreads();
  short8 qf[2][4];  // [nt][ks]: B-frag rows q = w*32 + nt*16 + l16
#pragma unroll
  for (int nt = 0; nt < 2; nt++)
#pragma unroll
    for (int ks = 0; ks < 4; ks++)
      qf[nt][ks] =
          *(const short8*)&smem[(ks * 4 + qd) * 1024 + (w * 32 + nt * 16 + l16) * 8];
  __syncthreads();

  // ---- stage KV tile 0 into buf 0: Ks @0 [c16][kv32][8], Vs @8192 [vc4][dh128][8]
#pragma unroll
  for (int i = 0; i < 2; i++) {
    const int p = i * 256 + tid;
    const int kr = p & 31, kc = p >> 5;
    lds_cp16(&smem[kc * 256 + kr * 8], kb + kbase + (size_t)kr * 1024 + kc * 8);
    const int dh = p & 127, vc = p >> 7;
    lds_cp16(&smem[8192 + vc * 1024 + dh * 8], vt + vbase + (size_t)dh * 2048 + vc * 8);
  }

  floatx4 oacc[8][2];  // O^T tiles [dh-tile][q-tile]
#pragma unroll
  for (int mt = 0; mt < 8; mt++)
#pragma unroll
    for (int nt = 0; nt < 2; nt++) { floatx4 z = {0.f, 0.f, 0.f, 0.f}; oacc[mt][nt] = z; }
  float lsum[2] = {0.f, 0.f};

  const int addrLo = ((qd & 1) * 32 + l16) * 4;  // src lane *4 for ds_bpermute
  const int addrHi = addrLo + 64;
  const bool loHalf = (lane < 32);

  for (int it = 0; it < 64; it++) {
    __syncthreads();
    if (it + 1 < 64) {
      const int nb = (it + 1) & 1, kv0 = (it + 1) * 32;
#pragma unroll
      for (int i = 0; i < 2; i++) {
        const int p = i * 256 + tid;
        const int kr = p & 31, kc = p >> 5;
        lds_cp16(&smem[nb * 4096 + kc * 256 + kr * 8],
                 kb + kbase + (size_t)(kv0 + kr) * 1024 + kc * 8);
        const int dh = p & 127, vc = p >> 7;
        lds_cp16(&smem[8192 + nb * 4096 + vc * 1024 + dh * 8],
                 vt + vbase + (size_t)dh * 2048 + kv0 + vc * 8);
      }
    }
    const int cur = it & 1;

    // S^T = K Q^T  (wave: 32 kv rows x its 32 q cols)
    floatx4 st[2][2];  // [kv-tile mt][q-tile nt]
#pragma unroll
    for (int mt = 0; mt < 2; mt++)
#pragma unroll
      for (int nt = 0; nt < 2; nt++) { floatx4 z = {0.f, 0.f, 0.f, 0.f}; st[mt][nt] = z; }
#pragma unroll
    for (int ks = 0; ks < 4; ks++) {
      const short8 ka = *(const short8*)&smem[cur * 4096 + (ks * 4 + qd) * 256 + l16 * 8];
      const short8 kb2 =
          *(const short8*)&smem[cur * 4096 + (ks * 4 + qd) * 256 + (16 + l16) * 8];
#pragma unroll
      for (int nt = 0; nt < 2; nt++) {
        st[0][nt] = __builtin_amdgcn_mfma_f32_16x16x32_bf16(ka, qf[nt][ks], st[0][nt], 0, 0, 0);
        st[1][nt] = __builtin_amdgcn_mfma_f32_16x16x32_bf16(kb2, qf[nt][ks], st[1][nt], 0, 0, 0);
      }
    }

    // P = exp(S^T/32): pack bf16 pairs, per-lane partial row-sums (over kv)
    uint32_t pk[2][2][2];
#pragma unroll
    for (int mt = 0; mt < 2; mt++)
#pragma unroll
      for (int nt = 0; nt < 2; nt++) {
        const float e0 = __expf(st[mt][nt][0] * 0.03125f);
        const float e1 = __expf(st[mt][nt][1] * 0.03125f);
        const float e2 = __expf(st[mt][nt][2] * 0.03125f);
        const float e3 = __expf(st[mt][nt][3] * 0.03125f);
        lsum[nt] += (e0 + e1) + (e2 + e3);
        pk[mt][nt][0] = __builtin_amdgcn_perm(fbits(e1), fbits(e0), 0x07060302);
        pk[mt][nt][1] = __builtin_amdgcn_perm(fbits(e3), fbits(e2), 0x07060302);
      }

    // Assemble P^T B-frags via quad redistribution, then O^T += V^T P^T
#pragma unroll
    for (int nt = 0; nt < 2; nt++) {
      int d0a = __builtin_amdgcn_ds_bpermute(addrLo, (int)pk[0][nt][0]);
      int d0b = __builtin_amdgcn_ds_bpermute(addrLo, (int)pk[1][nt][0]);
      int d1a = __builtin_amdgcn_ds_bpermute(addrLo, (int)pk[0][nt][1]);
      int d1b = __builtin_amdgcn_ds_bpermute(addrLo, (int)pk[1][nt][1]);
      int d2a = __builtin_amdgcn_ds_bpermute(addrHi, (int)pk[0][nt][0]);
      int d2b = __builtin_amdgcn_ds_bpermute(addrHi, (int)pk[1][nt][0]);
      int d3a = __builtin_amdgcn_ds_bpermute(addrHi, (int)pk[0][nt][1]);
      int d3b = __builtin_amdgcn_ds_bpermute(addrHi, (int)pk[1][nt][1]);
      union { int i[4]; short8 s; } u;
      u.i[0] = loHalf ? d0a : d0b;
      u.i[1] = loHalf ? d1a : d1b;
      u.i[2] = loHalf ? d2a : d2b;
      u.i[3] = loHalf ? d3a : d3b;
      const short8 pf = u.s;
#pragma unroll
      for (int mt = 0; mt < 8; mt++) {
        const short8 vf =
            *(const short8*)&smem[8192 + cur * 4096 + qd * 1024 + (mt * 16 + l16) * 8];
        oacc[mt][nt] = __builtin_amdgcn_mfma_f32_16x16x32_bf16(vf, pf, oacc[mt][nt], 0, 0, 0);
      }
    }
  }

  // finalize row sums (reduce over quads; q lives in l16)
  float inv[2];
#pragma unroll
  for (int nt = 0; nt < 2; nt++) {
    float s = lsum[nt];
    s += __shfl_xor(s, 16);
    s += __shfl_xor(s, 32);
    inv[nt] = 1.f / s;
  }

  // ---- transpose O^T back via XOR-swizzled LDS, add residual, store ----
  __syncthreads();  // all Vs reads done; smem reusable
#pragma unroll
  for (int mt = 0; mt < 8; mt++)
#pragma unroll
    for (int nt = 0; nt < 2; nt++) {
      const int q = w * 32 + nt * 16 + l16;
#pragma unroll
      for (int r = 0; r < 4; r++) {
        const int dh = mt * 16 + qd * 4 + r;
        const int c = dh >> 3, off = dh & 7;
        smem[q * 128 + ((c ^ (q & 15)) * 8) + off] = f2bf_trunc(oacc[mt][nt][r] * inv[nt]);
      }
    }
  __syncthreads();
#pragma unroll
  for (int i = 0; i < 8; i++) {
    const int p = i * 256 + tid;
    const int row = p >> 4, c = p & 15;
    const short8 ov = *(const short8*)&smem[row * 128 + ((c ^ (row & 15)) * 8)];
    const short8 qres = *(const short8*)(qb + qbase + (size_t)row * 1024 + c * 8);
    union { unsigned short us[8]; short8 s; } o;
#pragma unroll
    for (int e = 0; e < 8; e++)
      o.us[e] = f2bf(bf2f((unsigned short)ov[e]) + bf2f((unsigned short)qres[e]));
    *(short8*)(Ob + qbase + (size_t)row * 1024 + c * 8) = o.s;
  }
}

// =====================================================================
// Row LayerNorm over 1024 (bf16 -> bf16)
// =====================================================================
__global__ __launch_bounds__(256) void ln_rows(const unsigned short* __restrict__ X,
                                               const float* __restrict__ g,
                                               const float* __restrict__ bb,
                                               unsigned short* __restrict__ Y) {
  __shared__ float red[8];
  const int row = blockIdx.x, tid = threadIdx.x;
  const int w = tid >> 6, lane = tid & 63;
  const ushortx4 u = ((const ushortx4*)(X + (size_t)row * 1024))[tid];
  float x0 = bf2f(u.x), x1 = bf2f(u.y), x2 = bf2f(u.z), x3 = bf2f(u.w);
  float s = x0 + x1 + x2 + x3;
  float s2 = x0 * x0 + x1 * x1 + x2 * x2 + x3 * x3;
#pragma unroll
  for (int off = 1; off < 64; off <<= 1) { s += __shfl_xor(s, off); s2 += __shfl_xor(s2, off); }
  if (lane == 0) { red[w] = s; red[4 + w] = s2; }
  __syncthreads();
  s = red[0] + red[1] + red[2] + red[3];
  s2 = red[4] + red[5] + red[6] + red[7];
  const float mu = s * (1.f / 1024.f);
  const float rs = rsqrtf(s2 * (1.f / 1024.f) - mu * mu + 1e-5f);
  const floatx4 gv = ((const floatx4*)g)[tid];
  const floatx4 bv = ((const floatx4*)bb)[tid];
  ushortx4 o;
  o.x = f2bf((x0 - mu) * rs * gv.x + bv.x);
  o.y = f2bf((x1 - mu) * rs * gv.y + bv.y);
  o.z = f2bf((x2 - mu) * rs * gv.z + bv.z);
  o.w = f2bf((x3 - mu) * rs * gv.w + bv.w);
  ((ushortx4*)(Y + (size_t)row * 1024))[tid] = o;
}

// =====================================================================
// Row LayerNorm over 1024 (f32 -> f32) for the final output
// =====================================================================
__global__ __launch_bounds__(256) void ln_f32(const float* __restrict__ X,
                                              const float* __restrict__ g,
                                              const float* __restrict__ bb,
                                              float* __restrict__ out) {
  __shared__ float red[8];
  const int row = blockIdx.x, tid = threadIdx.x;
  const int w = tid >> 6, lane = tid & 63;
  const floatx4 xv = ((const floatx4*)(X + (size_t)row * 1024))[tid];
  float x0 = xv.x, x1 = xv.y, x2 = xv.z, x3 = xv.w;
  float s = x0 + x1 + x2 + x3;
  float s2 = x0 * x0 + x1 * x1 + x2 * x2 + x3 * x3;
#pragma unroll
  for (int off = 1; off < 64; off <<= 1) { s += __shfl_xor(s, off); s2 += __shfl_xor(s2, off); }
  if (lane == 0) { red[w] = s; red[4 + w] = s2; }
  __syncthreads();
  s = red[0] + red[1] + red[2] + red[3];
  s2 = red[4] + red[5] + red[6] + red[7];
  const float mu = s * (1.f / 1024.f);
  const float rs = rsqrtf(s2 * (1.f / 1024.f) - mu * mu + 1e-5f);
  const floatx4 gv = ((const floatx4*)g)[tid];
  const floatx4 bv = ((const floatx4*)bb)[tid];
  floatx4 o;
  o.x = (x0 - mu) * rs * gv.x + bv.x;
  o.y = (x1 - mu) * rs * gv.y + bv.y;
  o.z = (x2 - mu) * rs * gv.z + bv.z;
  o.w = (x3 - mu) * rs * gv.w + bv.w;
  ((floatx4*)(out + (size_t)row * 1024))[tid] = o;
}

// =====================================================================
// Host launch
// =====================================================================
extern "C" void kernel_launch(void* const* d_in, const int* in_sizes, int n_in,
                              void* d_out, int out_size, void* d_ws, size_t ws_size,
                              hipStream_t stream) {
  (void)in_sizes; (void)n_in; (void)out_size; (void)ws_size;
  const float* Q  = (const float*)d_in[0];
  const float* K  = (const float*)d_in[1];
  const float* Wq = (const float*)d_in[2];
  const float* bq = (const float*)d_in[3];
  const float* Wk = (const float*)d_in[4];
  const float* bk = (const float*)d_in[5];
  const float* Wv = (const float*)d_in[6];
  const float* bv = (const float*)d_in[7];
  const float* Wo = (const float*)d_in[8];
  const float* bo = (const float*)d_in[9];
  const float* g0 = (const float*)d_in[10];
  const float* b0 = (const float*)d_in[11];
  const float* g1 = (const float*)d_in[12];
  const float* b1 = (const float*)d_in[13];
  float* out = (float*)d_out;

  char* ws = (char*)d_ws;
  const size_t MB = 1u << 20;
  unsigned short* Qb  = (unsigned short*)(ws + 0);         // 16 MB [later: O bf16]
  unsigned short* X1  = (unsigned short*)(ws + 16 * MB);   // 16 MB
  unsigned short* Wt  = (unsigned short*)(ws + 32 * MB);   // 4 MB bf16 [Wq^T;Wo^T]
  unsigned char*  Wt8 = (unsigned char*)(ws + 36 * MB);    // 2 MB fp8 [Wk^T;Wv^T]
  unsigned char*  Kf8 = (unsigned char*)(ws + 38 * MB);    // 16 MB
  unsigned short* qbp = (unsigned short*)(ws + 54 * MB);   // 16 MB
  unsigned short* kbp = (unsigned short*)(ws + 70 * MB);   // 32 MB [later: O2 f32]
  unsigned short* vtp = (unsigned short*)(ws + 102 * MB);  // 32 MB
  unsigned short* O   = Qb;
  float* O2 = (float*)(ws + 70 * MB);

  unsigned short* Wqt = Wt;
  unsigned short* Wot = Wt + (size_t)1024 * 1024;

  cvt_qk<<<24576, 256, 0, stream>>>(Q, K, Qb, Kf8);
  wtrans4<<<dim3(32, 32, 4), dim3(32, 8), 0, stream>>>(Wq, Wk, Wv, Wo, Wt, Wt8);

  // Q projection -> qbp (bf16 rowmajor), 128x128 bf16, XCD m-banded
  gemm_bt<0><<<512, 256, 0, stream>>>(Qb, Wqt, bq, nullptr, qbp);
  // fused K+V projection in FP8 (M=16384, N=2048), XCD m-banded
  gemm_kv_f8<<<2048, 256, 0, stream>>>(Kf8, Wt8, bk, bv, kbp, vtp);
  // attention (+ q residual) -> O bf16, transposed-S formulation
  attn<<<512, 256, 0, stream>>>(qbp, kbp, vtp, O);
  // LN0
  ln_rows<<<8192, 256, 0, stream>>>(O, g0, b0, X1);
  // O2 = X1 + relu(X1 @ Wo + bo)  (f32), XCD m-banded
  gemm_bt<2><<<512, 256, 0, stream>>>(X1, Wot, bo, X1, O2);
  // out = LN(O2)
  ln_f32<<<8192, 256, 0, stream>>>(O2, g1, b1, out);
}